// Round 2
// baseline (122.592 us; speedup 1.0000x reference)
//
#include <hip/hip_runtime.h>

// Cost volume: out[b,d,h,w] = (1/C) * sum_c L[b,c,h,w] * R[b,c,h,w-d], zero for w<d.
// B=8, C=128, H=96, W=320, D=48, fp32.
//
// One block per (b,h). 320 threads: thread owns 4 consecutive w x 12 consecutive d.
// Per channel: the 12 d's x 4 w's need R[w-d] over a 15-float CONSECUTIVE window
// -> 4 aligned float4 LDS reads (+1 for L) per 48 FMAs. R rows are staged with a
// 48-float zero left-pad so the w<d boundary needs no branches.

constexpr int Cn = 128, Hn = 96, Wn = 320, Dn = 48;
constexpr int CC = 8;            // channel chunk staged in LDS
constexpr int RW = Wn + 48;      // padded R row = 368 floats (16B-aligned stride)

__global__ __launch_bounds__(320)
void costvol_kernel(const float* __restrict__ L, const float* __restrict__ R,
                    float* __restrict__ out) {
  const int bh = blockIdx.x;
  const int b = bh / Hn, h = bh % Hn;

  __shared__ float Ls[CC][Wn];
  __shared__ float Rs[CC][RW];

  const int tid = threadIdx.x;           // 0..319

  // Zero the 48-float left pad of each Rs row (persists across chunks).
  for (int i = tid; i < CC * 48; i += 320) Rs[i / 48][i % 48] = 0.f;

  const int wg = tid % 80, dg = tid / 80;      // 80 w-groups x 4 d-groups
  const int w0 = wg * 4, d0 = dg * 12;
  const int p0 = w0 - d0 + 36;                 // aligned (mod 4) window base in Rs

  float acc[12][4];
#pragma unroll
  for (int k = 0; k < 12; ++k)
#pragma unroll
    for (int i = 0; i < 4; ++i) acc[k][i] = 0.f;

  const size_t planeHW = (size_t)Hn * Wn;      // 30720
  const size_t baseBH = (size_t)b * Cn * planeHW + (size_t)h * Wn;

  // Staging: 640 float4 per array per chunk; thread does f = tid and tid+320.
  // f -> row = f/80 (channel within chunk), col = (f%80)*4. Coalesced 16B/lane.
  const int row0 = tid / 80, col0 = (tid % 80) * 4;
  const int row1 = row0 + 4, col1 = col0;
  const size_t cstep = (size_t)CC * planeHW;

  const float* Lp0 = L + baseBH + (size_t)row0 * planeHW + col0;
  const float* Lp1 = L + baseBH + (size_t)row1 * planeHW + col1;
  const float* Rp0 = R + baseBH + (size_t)row0 * planeHW + col0;
  const float* Rp1 = R + baseBH + (size_t)row1 * planeHW + col1;

  for (int c0 = 0; c0 < Cn; c0 += CC) {
    __syncthreads();   // previous chunk's compute done (and pad-zeroing on iter 0)
    const float4 l0 = *(const float4*)Lp0;  Lp0 += cstep;
    const float4 l1 = *(const float4*)Lp1;  Lp1 += cstep;
    const float4 r0 = *(const float4*)Rp0;  Rp0 += cstep;
    const float4 r1 = *(const float4*)Rp1;  Rp1 += cstep;
    *(float4*)&Ls[row0][col0] = l0;
    *(float4*)&Ls[row1][col1] = l1;
    *(float4*)&Rs[row0][48 + col0] = r0;
    *(float4*)&Rs[row1][48 + col1] = r1;
    __syncthreads();

#pragma unroll
    for (int cc = 0; cc < CC; ++cc) {
      const float4 lv = *(const float4*)&Ls[cc][w0];
      float q[16];
#pragma unroll
      for (int t = 0; t < 4; ++t) {
        const float4 qq = *(const float4*)&Rs[cc][p0 + 4 * t];
        q[4 * t + 0] = qq.x; q[4 * t + 1] = qq.y;
        q[4 * t + 2] = qq.z; q[4 * t + 3] = qq.w;
      }
      const float lw[4] = {lv.x, lv.y, lv.z, lv.w};
      // d = d0+k, w = w0+i needs R[w-d] = Rs[cc][w0+i-d0-k+48] = q[i-k+12]
#pragma unroll
      for (int k = 0; k < 12; ++k)
#pragma unroll
        for (int i = 0; i < 4; ++i)
          acc[k][i] += lw[i] * q[i - k + 12];
    }
  }

  // out[((b*D + d)*H + h)*W + w], mean over C -> *1/128
  float* obase = out + ((size_t)b * Dn + d0) * planeHW + (size_t)h * Wn + w0;
#pragma unroll
  for (int k = 0; k < 12; ++k) {
    float4 o;
    o.x = acc[k][0] * (1.f / 128.f);
    o.y = acc[k][1] * (1.f / 128.f);
    o.z = acc[k][2] * (1.f / 128.f);
    o.w = acc[k][3] * (1.f / 128.f);
    *(float4*)(obase + (size_t)k * planeHW) = o;
  }
}

extern "C" void kernel_launch(void* const* d_in, const int* in_sizes, int n_in,
                              void* d_out, int out_size, void* d_ws, size_t ws_size,
                              hipStream_t stream) {
  const float* Lf = (const float*)d_in[0];
  const float* Rf = (const float*)d_in[1];
  float* outp = (float*)d_out;
  const int B = 8;
  costvol_kernel<<<dim3(B * Hn), dim3(320), 0, stream>>>(Lf, Rf, outp);
}

// Round 3
// 99.924 us; speedup vs baseline: 1.2268x; 1.2268x over previous
//
#include <hip/hip_runtime.h>

// Cost volume: out[b,d,h,w] = (1/C) * sum_c L[b,c,h,w] * R[b,c,h,w-d], zero for w<d.
// B=8, C=128, H=96, W=320, D=48, fp32.
//
// One block per (b,h), 320 threads: thread owns 4 consecutive w x 12 consecutive d.
// Round 3: double-buffered LDS pipeline — issue next chunk's global loads BEFORE
// compute, ds_write them after compute, ONE barrier per chunk. Removes the
// exposed HBM latency that made round 2 latency-bound (VALUBusy 19%, all pipes idle).

constexpr int Cn = 128, Hn = 96, Wn = 320, Dn = 48;
constexpr int CC = 8;            // channel chunk staged in LDS
constexpr int RW = Wn + 48;      // padded R row = 368 floats
constexpr int NCH = Cn / CC;     // 16 chunks

__global__ __launch_bounds__(320)
void costvol_kernel(const float* __restrict__ L, const float* __restrict__ R,
                    float* __restrict__ out) {
  const int bh = blockIdx.x;
  const int b = bh / Hn, h = bh % Hn;

  __shared__ float Ls[2][CC][Wn];   // 20480 B
  __shared__ float Rs[2][CC][RW];   // 23552 B  (total 44 KB -> 3 blocks/CU, = grid limit)

  const int tid = threadIdx.x;

  // Zero the 48-float left pads of BOTH Rs buffers (written once, never touched again).
  for (int i = tid; i < 2 * CC * 48; i += 320)
    Rs[i / (CC * 48)][(i / 48) % CC][i % 48] = 0.f;

  const int wg = tid % 80, dg = tid / 80;      // 80 w-groups x 4 d-groups
  const int w0 = wg * 4, d0 = dg * 12;
  const int p0 = w0 - d0 + 36;                 // aligned (mod 4) window base in Rs

  float acc[12][4];
#pragma unroll
  for (int k = 0; k < 12; ++k)
#pragma unroll
    for (int i = 0; i < 4; ++i) acc[k][i] = 0.f;

  const size_t planeHW = (size_t)Hn * Wn;      // 30720
  const size_t baseBH = (size_t)b * Cn * planeHW + (size_t)h * Wn;

  // Staging map: f in {tid, tid+320} -> row=f/80 (channel in chunk), col=(f%80)*4.
  const int row0 = tid / 80, col0 = (tid % 80) * 4;
  const int row1 = row0 + 4;
  const size_t cstep = (size_t)CC * planeHW;

  const float* Lp0 = L + baseBH + (size_t)row0 * planeHW + col0;
  const float* Lp1 = L + baseBH + (size_t)row1 * planeHW + col0;
  const float* Rp0 = R + baseBH + (size_t)row0 * planeHW + col0;
  const float* Rp1 = R + baseBH + (size_t)row1 * planeHW + col0;

  // ---- prologue: stage chunk 0 into buffer 0 ----
  float4 l0 = *(const float4*)Lp0; Lp0 += cstep;
  float4 l1 = *(const float4*)Lp1; Lp1 += cstep;
  float4 r0 = *(const float4*)Rp0; Rp0 += cstep;
  float4 r1 = *(const float4*)Rp1; Rp1 += cstep;
  *(float4*)&Ls[0][row0][col0] = l0;
  *(float4*)&Ls[0][row1][col0] = l1;
  *(float4*)&Rs[0][row0][48 + col0] = r0;
  *(float4*)&Rs[0][row1][48 + col0] = r1;
  __syncthreads();

  int cur = 0;
  for (int t = 0; t < NCH; ++t) {
    const int nxt = cur ^ 1;

    // Issue next chunk's loads FIRST — they fly during the compute below.
    if (t + 1 < NCH) {
      l0 = *(const float4*)Lp0; Lp0 += cstep;
      l1 = *(const float4*)Lp1; Lp1 += cstep;
      r0 = *(const float4*)Rp0; Rp0 += cstep;
      r1 = *(const float4*)Rp1; Rp1 += cstep;
    }

    // Compute chunk t from buf[cur].
#pragma unroll
    for (int cc = 0; cc < CC; ++cc) {
      const float4 lv = *(const float4*)&Ls[cur][cc][w0];
      float q[16];
#pragma unroll
      for (int tt = 0; tt < 4; ++tt) {
        const float4 qq = *(const float4*)&Rs[cur][cc][p0 + 4 * tt];
        q[4 * tt + 0] = qq.x; q[4 * tt + 1] = qq.y;
        q[4 * tt + 2] = qq.z; q[4 * tt + 3] = qq.w;
      }
      const float lw[4] = {lv.x, lv.y, lv.z, lv.w};
      // d = d0+k, w = w0+i needs R[w-d] = Rs[cc][w0+i-d0-k+48] = q[i-k+12]
#pragma unroll
      for (int k = 0; k < 12; ++k)
#pragma unroll
        for (int i = 0; i < 4; ++i)
          acc[k][i] += lw[i] * q[i - k + 12];
    }

    // Write the prefetched chunk into buf[nxt] (compiler auto-waits vmcnt on the
    // register deps). buf[nxt] was last READ before the previous barrier — safe.
    if (t + 1 < NCH) {
      *(float4*)&Ls[nxt][row0][col0] = l0;
      *(float4*)&Ls[nxt][row1][col0] = l1;
      *(float4*)&Rs[nxt][row0][48 + col0] = r0;
      *(float4*)&Rs[nxt][row1][48 + col0] = r1;
      __syncthreads();   // one barrier per chunk
    }
    cur = nxt;
  }

  // out[((b*D + d)*H + h)*W + w], mean over C -> *1/128
  float* obase = out + ((size_t)b * Dn + d0) * planeHW + (size_t)h * Wn + w0;
#pragma unroll
  for (int k = 0; k < 12; ++k) {
    float4 o;
    o.x = acc[k][0] * (1.f / 128.f);
    o.y = acc[k][1] * (1.f / 128.f);
    o.z = acc[k][2] * (1.f / 128.f);
    o.w = acc[k][3] * (1.f / 128.f);
    *(float4*)(obase + (size_t)k * planeHW) = o;
  }
}

extern "C" void kernel_launch(void* const* d_in, const int* in_sizes, int n_in,
                              void* d_out, int out_size, void* d_ws, size_t ws_size,
                              hipStream_t stream) {
  const float* Lf = (const float*)d_in[0];
  const float* Rf = (const float*)d_in[1];
  float* outp = (float*)d_out;
  const int B = 8;
  costvol_kernel<<<dim3(B * Hn), dim3(320), 0, stream>>>(Lf, Rf, outp);
}